// Round 2
// baseline (133.195 us; speedup 1.0000x reference)
//
#include <hip/hip_runtime.h>

typedef unsigned short u16;
typedef __attribute__((ext_vector_type(8))) short bf16x8;
typedef __attribute__((ext_vector_type(8))) unsigned short u16x8;
typedef __attribute__((ext_vector_type(4))) float f32x4;

#define NROWS 131072

static __device__ __forceinline__ u16 f2bf(float f) {
  unsigned u = __float_as_uint(f);
  u += 0x7fffu + ((u >> 16) & 1u);   // RNE
  return (u16)(u >> 16);
}
static __device__ __forceinline__ float bf2f(u16 v) {
  return __uint_as_float(((unsigned)v) << 16);
}
static __device__ __forceinline__ float tanh_f(float x) {
  x = fminf(fmaxf(x, -15.f), 15.f);
  float e = __expf(2.f * x);
  return (e - 1.f) / (e + 1.f);
}

// ---------------- prep kernels (trivial cost) ----------------

// Wc = W0 @ W1 (fp32 accumulate), stored transposed bf16: wcT[c*256+k] = Wc[k][c]
__global__ void k_prep_wc(const float* __restrict__ W0,
                          const float* __restrict__ W1,
                          u16* __restrict__ wcT) {
  __shared__ float lw1[128 * 128];
  const int t = threadIdx.x;
  for (int i = t; i < 128 * 128; i += 256) lw1[i] = W1[i];
  __syncthreads();
  const int c = t & 127;
  for (int kk = (t >> 7); kk < 8; kk += 2) {
    const int k = blockIdx.x * 8 + kk;
    const float* w0r = W0 + k * 128;
    float a = 0.f;
#pragma unroll 8
    for (int j = 0; j < 128; j++) a = fmaf(w0r[j], lw1[j * 128 + c], a);
    wcT[c * 256 + k] = f2bf(a);
  }
}

// WheadT[col*128+k] = W_{col>>7}[k][col&127]  (head order g,f,h,tau), bf16
__global__ void k_prep_wh(const float* __restrict__ Wg, const float* __restrict__ Wf,
                          const float* __restrict__ Wh, const float* __restrict__ Wt,
                          u16* __restrict__ whT) {
  const int idx = blockIdx.x * 256 + threadIdx.x;  // 65536 total
  const int col = idx >> 7, k = idx & 127;
  const int hh = col >> 7, c = col & 127;
  const float* W = hh == 0 ? Wg : hh == 1 ? Wf : hh == 2 ? Wh : Wt;
  whT[col * 128 + k] = f2bf(W[k * 128 + c]);
}

// bias concat [512] + zero the global stat accumulators (replaces memset)
__global__ void k_prep_bias(const float* __restrict__ bg, const float* __restrict__ bf_,
                            const float* __restrict__ bh, const float* __restrict__ bt,
                            float* __restrict__ biasc, float* __restrict__ gstat) {
  const int t = threadIdx.x;  // 512
  const int hh = t >> 7, c = t & 127;
  const float* s = hh == 0 ? bg : hh == 1 ? bf_ : hh == 2 ? bh : bt;
  biasc[t] = s[c];
  if (t < 256) gstat[t] = 0.f;
}

// ---------------- pass 1: z = cat(x,h) @ Wc, bf16 z + column stats ----------------
// 512 threads = 8 waves, each wave: 16 rows x 128 cols. Block tile: 128 rows.
__global__ __launch_bounds__(512) void k_gemm1(
    const float* __restrict__ x, const float* __restrict__ h,
    const u16* __restrict__ wcT, u16* __restrict__ z,
    float* __restrict__ gstat) {
  __shared__ u16 lwc[128 * 256];        // 64KB, XOR-swizzled (T2)
  __shared__ float lsum[128], lsq[128];
  const int t = threadIdx.x;
  const int w = t >> 6, lane = t & 63;
  const int c15 = lane & 15, g = lane >> 4;

  if (t < 128) lsum[t] = 0.f;
  else if (t < 256) lsq[t - 128] = 0.f;

  // stage WcT -> LDS, swizzle byte ^= ((row&7)<<4); row = 512B = 32 chunks
  for (int q = t; q < 4096; q += 512) {
    const int c = q >> 5;
    const int dst = (q * 16) ^ ((c & 7) << 4);
    *(u16x8*)((char*)lwc + dst) = *(const u16x8*)((const char*)wcT + (size_t)q * 16);
  }
  __syncthreads();

  const long row = (long)blockIdx.x * 128 + w * 16 + c15;
  const float* xr = x + row * 128;
  const float* hr = h + row * 128;

  f32x4 acc[8];
#pragma unroll
  for (int n = 0; n < 8; n++) acc[n] = (f32x4){0.f, 0.f, 0.f, 0.f};

  // A-fragment 2-deep prefetch from global (each lane: 8 consecutive k, fp32)
  float4 pa[2], pb[2];
  {
    const float* p = xr + g * 8;
    pa[0] = *(const float4*)p;
    pb[0] = *(const float4*)(p + 4);
  }
#pragma unroll
  for (int ks = 0; ks < 8; ks++) {
    const int cur = ks & 1, nxt = cur ^ 1;
    if (ks < 7) {
      const float* src = (ks + 1 < 4) ? xr : hr;
      const float* p = src + (((ks + 1) & 3) * 32 + g * 8);
      pa[nxt] = *(const float4*)p;
      pb[nxt] = *(const float4*)(p + 4);
    }
    bf16x8 af;
    af[0] = (short)f2bf(pa[cur].x); af[1] = (short)f2bf(pa[cur].y);
    af[2] = (short)f2bf(pa[cur].z); af[3] = (short)f2bf(pa[cur].w);
    af[4] = (short)f2bf(pb[cur].x); af[5] = (short)f2bf(pb[cur].y);
    af[6] = (short)f2bf(pb[cur].z); af[7] = (short)f2bf(pb[cur].w);
#pragma unroll
    for (int n = 0; n < 8; n++) {
      const int col = n * 16 + c15;
      const int inner = ((ks * 32 + g * 8) * 2) ^ ((col & 7) << 4);
      const bf16x8 bfr = *(const bf16x8*)((const char*)lwc + col * 512 + inner);
      acc[n] = __builtin_amdgcn_mfma_f32_16x16x32_bf16(af, bfr, acc[n], 0, 0, 0);
    }
  }

  // write z (bf16, row-major). C layout: row=(lane>>4)*4+j, col=n*16+(lane&15)
  const long zrow = (long)blockIdx.x * 128 + w * 16 + g * 4;
#pragma unroll
  for (int n = 0; n < 8; n++) {
    const int col = n * 16 + c15;
#pragma unroll
    for (int j = 0; j < 4; j++) z[(zrow + j) * 128 + col] = f2bf(acc[n][j]);
  }

  // column sums / sumsq (fp32, pre-rounding): reduce rows within wave, then LDS, then global
#pragma unroll
  for (int n = 0; n < 8; n++) {
    float s0 = acc[n][0] + acc[n][1] + acc[n][2] + acc[n][3];
    float q0 = acc[n][0] * acc[n][0] + acc[n][1] * acc[n][1] +
               acc[n][2] * acc[n][2] + acc[n][3] * acc[n][3];
    s0 += __shfl_xor(s0, 16); s0 += __shfl_xor(s0, 32);
    q0 += __shfl_xor(q0, 16); q0 += __shfl_xor(q0, 32);
    if (g == 0) {
      atomicAdd(&lsum[n * 16 + c15], s0);
      atomicAdd(&lsq[n * 16 + c15], q0);
    }
  }
  __syncthreads();
  if (t < 128) {
    atomicAdd(&gstat[t], lsum[t]);
    atomicAdd(&gstat[128 + t], lsq[t]);
  }
}

// ---------------- BN fold: per-column scale/bias ----------------
__global__ void k_finalize(const float* __restrict__ gstat,
                           const float* __restrict__ gamma,
                           const float* __restrict__ beta,
                           float* __restrict__ sb) {
  const int c = threadIdx.x;
  const float inv = 1.f / (float)NROWS;
  const float mean = gstat[c] * inv;
  const float var = gstat[128 + c] * inv - mean * mean;
  const float s = gamma[c] * rsqrtf(var + 1e-5f);
  sb[c] = s;
  sb[128 + c] = beta[c] - mean * s;
}

// ---------------- pass 2: BN+LeakyReLU+4 head GEMMs+gated combine ----------------
// 512 threads = 8 waves (2 M x 4 C). Tile: 32 rows x 128 out-cols; each wave:
// 16 rows x 32 cols x all 4 heads -> combine is register-local.
#define HEAD_NT 8
__global__ __launch_bounds__(512) void k_head(
    const u16* __restrict__ z, const float* __restrict__ tvec,
    const u16* __restrict__ whT, const float* __restrict__ biasc,
    const float* __restrict__ sb, float* __restrict__ out) {
  __shared__ u16 lwh[512 * 128];  // 128KB, swizzled
  __shared__ u16 lzn[32 * 128];   // 8KB, swizzled
  __shared__ float ls[128], lb[128];
  const int t = threadIdx.x;
  const int w = t >> 6, lane = t & 63;
  const int c15 = lane & 15, g = lane >> 4;
  const int mw = w >> 2, cw = w & 3;

  const long tile0 = (long)blockIdx.x * HEAD_NT;
  const int zrow = t >> 4, zci = (t & 15) * 8;

  // prefetch first z chunk before the heavy WheadT stage (hides HBM latency)
  u16x8 zreg = *(const u16x8*)(z + (tile0 * 32 + zrow) * 128 + zci);

  for (int q = t; q < 8192; q += 512) {   // 131072B / 16
    const int col = q >> 4;               // 256B per row
    const int dst = (q * 16) ^ ((col & 7) << 4);
    *(u16x8*)((char*)lwh + dst) = *(const u16x8*)((const char*)whT + (size_t)q * 16);
  }
  if (t < 128) { ls[t] = sb[t]; lb[t] = sb[128 + t]; }

  // hoist per-lane head biases: fi = h*2+p
  float biasr[8];
#pragma unroll
  for (int fi = 0; fi < 8; fi++) {
    const int hh = fi >> 1, p = fi & 1;
    biasr[fi] = biasc[hh * 128 + cw * 32 + p * 16 + c15];
  }

  for (int it = 0; it < HEAD_NT; it++) {
    const long r0 = (tile0 + it) * 32;
    __syncthreads();  // staging done (it=0) / previous compute done reading lzn
    {
      u16x8 zn;
#pragma unroll
      for (int e = 0; e < 8; e++) {
        const int k = zci + e;
        float f = bf2f(zreg[e]) * ls[k] + lb[k];
        f = f > 0.f ? f : 0.01f * f;   // LeakyReLU
        zn[e] = (u16)f2bf(f);
      }
      const int dst = (zrow * 256 + zci * 2) ^ ((zrow & 7) << 4);
      *(u16x8*)((char*)lzn + dst) = zn;
    }
    if (it < HEAD_NT - 1)  // prefetch next tile's z (overlaps MFMA+combine)
      zreg = *(const u16x8*)(z + ((tile0 + it + 1) * 32 + zrow) * 128 + zci);
    __syncthreads();

    f32x4 acc[8];
#pragma unroll
    for (int fi = 0; fi < 8; fi++) acc[fi] = (f32x4){0.f, 0.f, 0.f, 0.f};
#pragma unroll
    for (int ks = 0; ks < 4; ks++) {
      const int rowl = mw * 16 + c15;
      const int ainner = ((ks * 32 + g * 8) * 2) ^ ((rowl & 7) << 4);
      const bf16x8 af = *(const bf16x8*)((const char*)lzn + rowl * 256 + ainner);
#pragma unroll
      for (int fi = 0; fi < 8; fi++) {
        const int hh = fi >> 1, p = fi & 1;
        const int colg = hh * 128 + cw * 32 + p * 16 + c15;
        const int binner = ((ks * 32 + g * 8) * 2) ^ ((colg & 7) << 4);
        const bf16x8 bfr = *(const bf16x8*)((const char*)lwh + colg * 256 + binner);
        acc[fi] = __builtin_amdgcn_mfma_f32_16x16x32_bf16(af, bfr, acc[fi], 0, 0, 0);
      }
    }

    // gated combine; all 4 head values for (r,c) live in this lane
#pragma unroll
    for (int j = 0; j < 4; j++) {
      const long row = r0 + mw * 16 + g * 4 + j;
      const float tv = tvec[row];
#pragma unroll
      for (int p = 0; p < 2; p++) {
        const float ug = acc[0 + p][j] + biasr[0 + p];
        const float uf = acc[2 + p][j] + biasr[2 + p];
        const float uh = acc[4 + p][j] + biasr[4 + p];
        const float ut = acc[6 + p][j] + biasr[6 + p];
        const float gg = tanh_f(ug);
        const float hv = tanh_f(uh);
        const float a = (ut + uf) * tv;
        const float sig = 1.f / (1.f + __expf(-a));
        out[row * 128 + cw * 32 + p * 16 + c15] = hv + sig * (gg - hv);
      }
    }
  }
}

// ---------------- launch ----------------
extern "C" void kernel_launch(void* const* d_in, const int* in_sizes, int n_in,
                              void* d_out, int out_size, void* d_ws, size_t ws_size,
                              hipStream_t stream) {
  const float* x     = (const float*)d_in[0];
  const float* h     = (const float*)d_in[1];
  const float* tv    = (const float*)d_in[2];
  const float* W0    = (const float*)d_in[3];
  const float* W1    = (const float*)d_in[4];
  const float* gamma = (const float*)d_in[5];
  const float* beta  = (const float*)d_in[6];
  const float* Wg    = (const float*)d_in[7];
  const float* bg    = (const float*)d_in[8];
  const float* Wf    = (const float*)d_in[9];
  const float* bf_   = (const float*)d_in[10];
  const float* Wh    = (const float*)d_in[11];
  const float* bh    = (const float*)d_in[12];
  const float* Wt    = (const float*)d_in[13];
  const float* bt    = (const float*)d_in[14];

  char* ws = (char*)d_ws;
  const size_t OFF_Z    = 0;                       // 131072*128*2 = 33554432
  const size_t OFF_WC   = 33554432;                // 65536
  const size_t OFF_WH   = OFF_WC + 65536;          // 131072
  const size_t OFF_BIAS = OFF_WH + 131072;         // 2048
  const size_t OFF_STAT = OFF_BIAS + 2048;         // 1024
  const size_t OFF_SB   = OFF_STAT + 1024;         // 1024
  u16*   zbuf  = (u16*)(ws + OFF_Z);
  u16*   wcT   = (u16*)(ws + OFF_WC);
  u16*   whT   = (u16*)(ws + OFF_WH);
  float* biasc = (float*)(ws + OFF_BIAS);
  float* gstat = (float*)(ws + OFF_STAT);
  float* sb    = (float*)(ws + OFF_SB);

  hipLaunchKernelGGL(k_prep_wc,   dim3(32),   dim3(256), 0, stream, W0, W1, wcT);
  hipLaunchKernelGGL(k_prep_wh,   dim3(256),  dim3(256), 0, stream, Wg, Wf, Wh, Wt, whT);
  hipLaunchKernelGGL(k_prep_bias, dim3(1),    dim3(512), 0, stream, bg, bf_, bh, bt, biasc, gstat);
  hipLaunchKernelGGL(k_gemm1,     dim3(1024), dim3(512), 0, stream, x, h, wcT, zbuf, gstat);
  hipLaunchKernelGGL(k_finalize,  dim3(1),    dim3(128), 0, stream, gstat, gamma, beta, sb);
  hipLaunchKernelGGL(k_head,      dim3(512),  dim3(512), 0, stream, zbuf, tv, whT, biasc, sb, (float*)d_out);
}

// Round 4
// 107.053 us; speedup vs baseline: 1.2442x; 1.2442x over previous
//
#include <hip/hip_runtime.h>

typedef unsigned short u16;
typedef __attribute__((ext_vector_type(8))) short bf16x8;
typedef __attribute__((ext_vector_type(8))) unsigned short u16x8;
typedef __attribute__((ext_vector_type(4))) float f32x4;

#define NROWS 131072

static __device__ __forceinline__ u16 f2bf(float f) {
  unsigned u = __float_as_uint(f);
  u += 0x7fffu + ((u >> 16) & 1u);   // RNE (prep-path only)
  return (u16)(u >> 16);
}
static __device__ __forceinline__ float bf2f(u16 v) {
  return __uint_as_float(((unsigned)v) << 16);
}
// HW packed RNE convert: low16 = bf16(lo), high16 = bf16(hi)  [guide T12/m240]
static __device__ __forceinline__ unsigned cvtpk(float lo, float hi) {
  unsigned r;
  asm("v_cvt_pk_bf16_f32 %0, %1, %2" : "=v"(r) : "v"(lo), "v"(hi));
  return r;
}
static __device__ __forceinline__ float tanh_f(float x) {
  x = fminf(fmaxf(x, -15.f), 15.f);
  float e = __expf(2.f * x);
  return (e - 1.f) / (e + 1.f);
}

// ---------------- prep kernels ----------------

// Wc = W0 @ W1 (fp32 accumulate), stored transposed bf16: wcT[c*256+k] = Wc[k][c]
__global__ void k_prep_wc(const float* __restrict__ W0,
                          const float* __restrict__ W1,
                          u16* __restrict__ wcT) {
  __shared__ float lw1[128 * 128];
  const int t = threadIdx.x;
  for (int i = t; i < 128 * 128; i += 256) lw1[i] = W1[i];
  __syncthreads();
  const int c = t & 127;
  for (int kk = (t >> 7); kk < 8; kk += 2) {
    const int k = blockIdx.x * 8 + kk;
    const float* w0r = W0 + k * 128;
    float a = 0.f;
#pragma unroll 8
    for (int j = 0; j < 128; j++) a = fmaf(w0r[j], lw1[j * 128 + c], a);
    wcT[c * 256 + k] = f2bf(a);
  }
}

// WheadT[col*128+k] = W_{col>>7}[k][col&127] bf16; + bias concat + zero gstatR
__global__ void k_prep_wh(const float* __restrict__ Wg, const float* __restrict__ Wf,
                          const float* __restrict__ Wh, const float* __restrict__ Wt,
                          u16* __restrict__ whT,
                          const float* __restrict__ bg, const float* __restrict__ bf_,
                          const float* __restrict__ bh, const float* __restrict__ bt,
                          float* __restrict__ biasc, float* __restrict__ gstatR) {
  const int idx = blockIdx.x * 256 + threadIdx.x;  // 65536 total
  const int col = idx >> 7, k = idx & 127;
  const int hh = col >> 7, c = col & 127;
  const float* W = hh == 0 ? Wg : hh == 1 ? Wf : hh == 2 ? Wh : Wt;
  whT[col * 128 + k] = f2bf(W[k * 128 + c]);
  if (blockIdx.x < 32) gstatR[blockIdx.x * 256 + threadIdx.x] = 0.f;  // 32 replicas x 256
  if (blockIdx.x == 32) {
    for (int i = threadIdx.x; i < 512; i += 256) {
      const int h2 = i >> 7, c2 = i & 127;
      const float* s = h2 == 0 ? bg : h2 == 1 ? bf_ : h2 == 2 ? bh : bt;
      biasc[i] = s[c2];
    }
  }
}

// ---------------- pass 1: z = cat(x,h) @ Wc (bf16 z + column stats) ----------------
// grid 512, 8 waves/block, 2 row-tiles of 128 per block, 2 blocks/CU.
__global__ __launch_bounds__(512, 4) void k_gemm1(
    const float* __restrict__ x, const float* __restrict__ h,
    const u16* __restrict__ wcT, u16* __restrict__ z,
    float* __restrict__ gstatR) {
  __shared__ u16 lwc[128 * 256];        // 64KB, XOR-swizzled
  __shared__ float lsum[128], lsq[128];
  const int t = threadIdx.x;
  const int w = t >> 6, lane = t & 63;
  const int c15 = lane & 15, g = lane >> 4;

  if (t < 128) lsum[t] = 0.f;
  else if (t < 256) lsq[t - 128] = 0.f;

  for (int q = t; q < 4096; q += 512) {   // stage WcT (16B chunks)
    const int c = q >> 5;
    const int dst = (q * 16) ^ ((c & 7) << 4);
    *(u16x8*)((char*)lwc + dst) = *(const u16x8*)((const char*)wcT + (size_t)q * 16);
  }
  __syncthreads();

  float sreg[8], qreg[8];
#pragma unroll
  for (int n = 0; n < 8; n++) { sreg[n] = 0.f; qreg[n] = 0.f; }

#pragma unroll 1
  for (int tile = 0; tile < 2; tile++) {
    const long row = (long)blockIdx.x * 256 + tile * 128 + w * 16 + c15;
    const float* xr = x + row * 128;
    const float* hr = h + row * 128;

    // 6-chunk ring: 12 x float4 in flight (chunks 0-3 = x, 4-5 = h)
    float4 a[12];
#pragma unroll
    for (int i = 0; i < 6; i++) {
      const float* p = (i < 4 ? xr + i * 32 : hr + (i - 4) * 32) + g * 8;
      a[2 * i] = *(const float4*)p;
      a[2 * i + 1] = *(const float4*)(p + 4);
    }

    f32x4 acc[8];
#pragma unroll
    for (int n = 0; n < 8; n++) acc[n] = (f32x4){0.f, 0.f, 0.f, 0.f};

#pragma unroll
    for (int ks = 0; ks < 8; ks++) {
      const int sl = (ks % 6) * 2;
      union { bf16x8 v; unsigned u[4]; } U;
      U.u[0] = cvtpk(a[sl].x, a[sl].y);
      U.u[1] = cvtpk(a[sl].z, a[sl].w);
      U.u[2] = cvtpk(a[sl + 1].x, a[sl + 1].y);
      U.u[3] = cvtpk(a[sl + 1].z, a[sl + 1].w);
      if (ks < 2) {  // prefetch h-chunk ks+6 into the slot just consumed
        const float* p = hr + (ks + 2) * 32 + g * 8;
        a[2 * ks] = *(const float4*)p;
        a[2 * ks + 1] = *(const float4*)(p + 4);
      }
#pragma unroll
      for (int n = 0; n < 8; n++) {
        const int col = n * 16 + c15;
        const int inner = ((ks * 32 + g * 8) * 2) ^ ((col & 7) << 4);
        const bf16x8 bfr = *(const bf16x8*)((const char*)lwc + col * 512 + inner);
        acc[n] = __builtin_amdgcn_mfma_f32_16x16x32_bf16(U.v, bfr, acc[n], 0, 0, 0);
      }
    }

    // z write (bf16): C layout row=(lane>>4)*4+j, col=n*16+(lane&15)
    const long zrow = (long)blockIdx.x * 256 + tile * 128 + w * 16 + g * 4;
#pragma unroll
    for (int n = 0; n < 8; n++) {
      const int col = n * 16 + c15;
#pragma unroll
      for (int jp = 0; jp < 4; jp += 2) {
        const unsigned pk = cvtpk(acc[n][jp], acc[n][jp + 1]);
        z[(zrow + jp) * 128 + col] = (u16)pk;
        z[(zrow + jp + 1) * 128 + col] = (u16)(pk >> 16);
      }
      sreg[n] += acc[n][0] + acc[n][1] + acc[n][2] + acc[n][3];
      qreg[n] += acc[n][0] * acc[n][0] + acc[n][1] * acc[n][1] +
                 acc[n][2] * acc[n][2] + acc[n][3] * acc[n][3];
    }
  }

#pragma unroll
  for (int n = 0; n < 8; n++) {
    float s0 = sreg[n], q0 = qreg[n];
    s0 += __shfl_xor(s0, 16); s0 += __shfl_xor(s0, 32);
    q0 += __shfl_xor(q0, 16); q0 += __shfl_xor(q0, 32);
    if (g == 0) {
      atomicAdd(&lsum[n * 16 + c15], s0);
      atomicAdd(&lsq[n * 16 + c15], q0);
    }
  }
  __syncthreads();
  if (t < 128) {
    float* dst = gstatR + (blockIdx.x & 31) * 256;  // 32-way replicated stats
    atomicAdd(&dst[t], lsum[t]);
    atomicAdd(&dst[128 + t], lsq[t]);
  }
}

// ---------------- pass 2: BN+LeakyReLU+4 head GEMMs+gated combine ----------------
// grid 256, 8 waves (2M x 4C), 16 tiles of 32 rows, dbuf zn -> 1 barrier/tile.
#define HEAD_NT 16
__global__ __launch_bounds__(512) void k_head(
    const u16* __restrict__ z, const float* __restrict__ tvec,
    const u16* __restrict__ whT, const float* __restrict__ biasc,
    const float* __restrict__ gstatR, const float* __restrict__ gamma,
    const float* __restrict__ beta, float* __restrict__ out) {
  __shared__ u16 lwh[512 * 128];     // 128KB, swizzled
  __shared__ u16 lzn[2][32 * 128];   // 2 x 8KB, swizzled
  __shared__ float ls[128], lb[128];
  const int t = threadIdx.x;
  const int w = t >> 6, lane = t & 63;
  const int c15 = lane & 15, g = lane >> 4;
  const int mw = w >> 2, cw = w & 3;

  const long tile0 = (long)blockIdx.x * HEAD_NT;
  const int zrow = t >> 4, zci = (t & 15) * 8;

  // prefetch first z chunk before the heavy WheadT stage
  u16x8 zreg = *(const u16x8*)(z + (tile0 * 32 + zrow) * 128 + zci);

  for (int q = t; q < 8192; q += 512) {   // stage WheadT
    const int col = q >> 4;
    const int dst = (q * 16) ^ ((col & 7) << 4);
    *(u16x8*)((char*)lwh + dst) = *(const u16x8*)((const char*)whT + (size_t)q * 16);
  }
  // BN finalize folded in: reduce 32 stat replicas
  if (t < 128) {
    float s = 0.f, q = 0.f;
#pragma unroll
    for (int r = 0; r < 32; r++) {
      s += gstatR[r * 256 + t];
      q += gstatR[r * 256 + 128 + t];
    }
    const float inv = 1.f / (float)NROWS;
    const float mean = s * inv;
    const float var = q * inv - mean * mean;
    const float sc = gamma[t] * rsqrtf(var + 1e-5f);
    ls[t] = sc;
    lb[t] = beta[t] - mean * sc;
  }

  float biasr[8];
#pragma unroll
  for (int fi = 0; fi < 8; fi++) {
    const int hh = fi >> 1, p = fi & 1;
    biasr[fi] = biasc[hh * 128 + cw * 32 + p * 16 + c15];
  }
  __syncthreads();  // ls/lb ready (staging covered by first in-loop barrier too)

  for (int it = 0; it < HEAD_NT; it++) {
    const long r0 = (tile0 + it) * 32;
    const int pb = it & 1;
    {  // BN + LeakyReLU -> bf16 -> swizzled LDS (dbuf)
      union { u16x8 v; unsigned u[4]; } Z;
#pragma unroll
      for (int e = 0; e < 8; e += 2) {
        const int k = zci + e;
        float f0 = bf2f(zreg[e]) * ls[k] + lb[k];
        float f1 = bf2f(zreg[e + 1]) * ls[k + 1] + lb[k + 1];
        f0 = f0 > 0.f ? f0 : 0.01f * f0;
        f1 = f1 > 0.f ? f1 : 0.01f * f1;
        Z.u[e >> 1] = cvtpk(f0, f1);
      }
      const int dst = (zrow * 256 + zci * 2) ^ ((zrow & 7) << 4);
      *(u16x8*)((char*)lzn[pb] + dst) = Z.v;
    }
    if (it < HEAD_NT - 1)  // prefetch next tile's z (overlaps barrier+MFMA)
      zreg = *(const u16x8*)(z + ((tile0 + it + 1) * 32 + zrow) * 128 + zci);
    const float4 tq = *(const float4*)(tvec + r0 + mw * 16 + g * 4);
    __syncthreads();  // zn[pb] written; (it=0: also lwh staged)

    f32x4 acc[8];
#pragma unroll
    for (int fi = 0; fi < 8; fi++) acc[fi] = (f32x4){0.f, 0.f, 0.f, 0.f};
#pragma unroll
    for (int ks = 0; ks < 4; ks++) {
      const int rowl = mw * 16 + c15;
      const int ainner = ((ks * 32 + g * 8) * 2) ^ ((rowl & 7) << 4);
      const bf16x8 af = *(const bf16x8*)((const char*)lzn[pb] + rowl * 256 + ainner);
#pragma unroll
      for (int fi = 0; fi < 8; fi++) {
        const int hh = fi >> 1, p = fi & 1;
        const int colg = hh * 128 + cw * 32 + p * 16 + c15;
        const int binner = ((ks * 32 + g * 8) * 2) ^ ((colg & 7) << 4);
        const bf16x8 bfr = *(const bf16x8*)((const char*)lwh + colg * 256 + binner);
        acc[fi] = __builtin_amdgcn_mfma_f32_16x16x32_bf16(af, bfr, acc[fi], 0, 0, 0);
      }
    }

#pragma unroll
    for (int j = 0; j < 4; j++) {
      const long row = r0 + mw * 16 + g * 4 + j;
      const float tv = tq[j];
#pragma unroll
      for (int p = 0; p < 2; p++) {
        const float ug = acc[0 + p][j] + biasr[0 + p];
        const float uf = acc[2 + p][j] + biasr[2 + p];
        const float uh = acc[4 + p][j] + biasr[4 + p];
        const float ut = acc[6 + p][j] + biasr[6 + p];
        const float gg = tanh_f(ug);
        const float hv = tanh_f(uh);
        const float aa = (ut + uf) * tv;
        const float sig = 1.f / (1.f + __expf(-aa));
        out[row * 128 + cw * 32 + p * 16 + c15] = hv + sig * (gg - hv);
      }
    }
  }
}

// ---------------- launch ----------------
extern "C" void kernel_launch(void* const* d_in, const int* in_sizes, int n_in,
                              void* d_out, int out_size, void* d_ws, size_t ws_size,
                              hipStream_t stream) {
  const float* x     = (const float*)d_in[0];
  const float* h     = (const float*)d_in[1];
  const float* tv    = (const float*)d_in[2];
  const float* W0    = (const float*)d_in[3];
  const float* W1    = (const float*)d_in[4];
  const float* gamma = (const float*)d_in[5];
  const float* beta  = (const float*)d_in[6];
  const float* Wg    = (const float*)d_in[7];
  const float* bg    = (const float*)d_in[8];
  const float* Wf    = (const float*)d_in[9];
  const float* bf_   = (const float*)d_in[10];
  const float* Wh    = (const float*)d_in[11];
  const float* bh    = (const float*)d_in[12];
  const float* Wt    = (const float*)d_in[13];
  const float* bt    = (const float*)d_in[14];

  char* ws = (char*)d_ws;
  const size_t OFF_Z    = 0;                       // 33554432
  const size_t OFF_WC   = 33554432;                // 65536
  const size_t OFF_WH   = OFF_WC + 65536;          // 131072
  const size_t OFF_BIAS = OFF_WH + 131072;         // 2048
  const size_t OFF_STAT = OFF_BIAS + 2048;         // 32*256*4 = 32768
  u16*   zbuf  = (u16*)(ws + OFF_Z);
  u16*   wcT   = (u16*)(ws + OFF_WC);
  u16*   whT   = (u16*)(ws + OFF_WH);
  float* biasc = (float*)(ws + OFF_BIAS);
  float* gstat = (float*)(ws + OFF_STAT);

  hipLaunchKernelGGL(k_prep_wc, dim3(32),  dim3(256), 0, stream, W0, W1, wcT);
  hipLaunchKernelGGL(k_prep_wh, dim3(256), dim3(256), 0, stream,
                     Wg, Wf, Wh, Wt, whT, bg, bf_, bh, bt, biasc, gstat);
  hipLaunchKernelGGL(k_gemm1,   dim3(512), dim3(512), 0, stream, x, h, wcT, zbuf, gstat);
  hipLaunchKernelGGL(k_head,    dim3(256), dim3(512), 0, stream,
                     zbuf, tv, whT, biasc, gstat, gamma, beta, (float*)d_out);
}

// Round 6
// 88.031 us; speedup vs baseline: 1.5131x; 1.2161x over previous
//
#include <hip/hip_runtime.h>

typedef unsigned short u16;
typedef __attribute__((ext_vector_type(8))) short bf16x8;
typedef __attribute__((ext_vector_type(8))) unsigned short u16x8;
typedef __attribute__((ext_vector_type(4))) float f32x4;

#define NROWS 131072

static __device__ __forceinline__ u16 f2bf(float f) {
  unsigned u = __float_as_uint(f);
  u += 0x7fffu + ((u >> 16) & 1u);   // RNE (prep-path only)
  return (u16)(u >> 16);
}
static __device__ __forceinline__ float bf2f(u16 v) {
  return __uint_as_float(((unsigned)v) << 16);
}
// HW packed RNE convert: low16 = bf16(lo), high16 = bf16(hi)
static __device__ __forceinline__ unsigned cvtpk(float lo, float hi) {
  unsigned r;
  asm("v_cvt_pk_bf16_f32 %0, %1, %2" : "=v"(r) : "v"(lo), "v"(hi));
  return r;
}
// fast reciprocal (v_rcp_f32, ~1e-7 rel err — fine vs 2% threshold)
static __device__ __forceinline__ float frcp(float x) {
  float r;
  asm("v_rcp_f32 %0, %1" : "=v"(r) : "v"(x));
  return r;
}
static __device__ __forceinline__ float tanh_f(float x) {
  x = fminf(fmaxf(x, -15.f), 15.f);
  const float t = __expf(2.f * x);
  return (t - 1.f) * frcp(t + 1.f);
}

// ---------------- prep kernels ----------------

__global__ void k_prep_wc(const float* __restrict__ W0,
                          const float* __restrict__ W1,
                          u16* __restrict__ wcT) {
  __shared__ float lw1[128 * 128];
  const int t = threadIdx.x;
  for (int i = t; i < 128 * 128; i += 256) lw1[i] = W1[i];
  __syncthreads();
  const int c = t & 127;
  for (int kk = (t >> 7); kk < 8; kk += 2) {
    const int k = blockIdx.x * 8 + kk;
    const float* w0r = W0 + k * 128;
    float a = 0.f;
#pragma unroll 8
    for (int j = 0; j < 128; j++) a = fmaf(w0r[j], lw1[j * 128 + c], a);
    wcT[c * 256 + k] = f2bf(a);
  }
}

__global__ void k_prep_wh(const float* __restrict__ Wg, const float* __restrict__ Wf,
                          const float* __restrict__ Wh, const float* __restrict__ Wt,
                          u16* __restrict__ whT,
                          const float* __restrict__ bg, const float* __restrict__ bf_,
                          const float* __restrict__ bh, const float* __restrict__ bt,
                          float* __restrict__ biasc, float* __restrict__ gstatR) {
  const int idx = blockIdx.x * 256 + threadIdx.x;  // 65536 total
  const int col = idx >> 7, k = idx & 127;
  const int hh = col >> 7, c = col & 127;
  const float* W = hh == 0 ? Wg : hh == 1 ? Wf : hh == 2 ? Wh : Wt;
  whT[col * 128 + k] = f2bf(W[k * 128 + c]);
  if (blockIdx.x < 32) gstatR[blockIdx.x * 256 + threadIdx.x] = 0.f;  // 32 replicas
  if (blockIdx.x == 32) {
    for (int i = threadIdx.x; i < 512; i += 256) {
      const int h2 = i >> 7, c2 = i & 127;
      const float* s = h2 == 0 ? bg : h2 == 1 ? bf_ : h2 == 2 ? bh : bt;
      biasc[i] = s[c2];
    }
  }
}

// ---------------- pass 1: z = cat(x,h) @ Wc (bf16 z + column stats) ----------------
// ROUND-4 VERBATIM (known-pass). grid 512, 8 waves, 2 row-tiles of 128.
__global__ __launch_bounds__(512, 4) void k_gemm1(
    const float* __restrict__ x, const float* __restrict__ h,
    const u16* __restrict__ wcT, u16* __restrict__ z,
    float* __restrict__ gstatR) {
  __shared__ u16 lwc[128 * 256];        // 64KB, XOR-swizzled
  __shared__ float lsum[128], lsq[128];
  const int t = threadIdx.x;
  const int w = t >> 6, lane = t & 63;
  const int c15 = lane & 15, g = lane >> 4;

  if (t < 128) lsum[t] = 0.f;
  else if (t < 256) lsq[t - 128] = 0.f;

  for (int q = t; q < 4096; q += 512) {   // stage WcT (16B chunks)
    const int c = q >> 5;
    const int dst = (q * 16) ^ ((c & 7) << 4);
    *(u16x8*)((char*)lwc + dst) = *(const u16x8*)((const char*)wcT + (size_t)q * 16);
  }
  __syncthreads();

  float sreg[8], qreg[8];
#pragma unroll
  for (int n = 0; n < 8; n++) { sreg[n] = 0.f; qreg[n] = 0.f; }

#pragma unroll 1
  for (int tile = 0; tile < 2; tile++) {
    const long row = (long)blockIdx.x * 256 + tile * 128 + w * 16 + c15;
    const float* xr = x + row * 128;
    const float* hr = h + row * 128;

    // 6-chunk ring: 12 x float4 in flight (chunks 0-3 = x, 4-5 = h)
    float4 a[12];
#pragma unroll
    for (int i = 0; i < 6; i++) {
      const float* p = (i < 4 ? xr + i * 32 : hr + (i - 4) * 32) + g * 8;
      a[2 * i] = *(const float4*)p;
      a[2 * i + 1] = *(const float4*)(p + 4);
    }

    f32x4 acc[8];
#pragma unroll
    for (int n = 0; n < 8; n++) acc[n] = (f32x4){0.f, 0.f, 0.f, 0.f};

#pragma unroll
    for (int ks = 0; ks < 8; ks++) {
      const int sl = (ks % 6) * 2;
      union { bf16x8 v; unsigned u[4]; } U;
      U.u[0] = cvtpk(a[sl].x, a[sl].y);
      U.u[1] = cvtpk(a[sl].z, a[sl].w);
      U.u[2] = cvtpk(a[sl + 1].x, a[sl + 1].y);
      U.u[3] = cvtpk(a[sl + 1].z, a[sl + 1].w);
      if (ks < 2) {  // prefetch h-chunk ks+6 into the slot just consumed
        const float* p = hr + (ks + 2) * 32 + g * 8;
        a[2 * ks] = *(const float4*)p;
        a[2 * ks + 1] = *(const float4*)(p + 4);
      }
#pragma unroll
      for (int n = 0; n < 8; n++) {
        const int col = n * 16 + c15;
        const int inner = ((ks * 32 + g * 8) * 2) ^ ((col & 7) << 4);
        const bf16x8 bfr = *(const bf16x8*)((const char*)lwc + col * 512 + inner);
        acc[n] = __builtin_amdgcn_mfma_f32_16x16x32_bf16(U.v, bfr, acc[n], 0, 0, 0);
      }
    }

    // z write (bf16): C layout row=(lane>>4)*4+j, col=n*16+(lane&15)
    const long zrow = (long)blockIdx.x * 256 + tile * 128 + w * 16 + g * 4;
#pragma unroll
    for (int n = 0; n < 8; n++) {
      const int col = n * 16 + c15;
#pragma unroll
      for (int jp = 0; jp < 4; jp += 2) {
        const unsigned pk = cvtpk(acc[n][jp], acc[n][jp + 1]);
        z[(zrow + jp) * 128 + col] = (u16)pk;
        z[(zrow + jp + 1) * 128 + col] = (u16)(pk >> 16);
      }
      sreg[n] += acc[n][0] + acc[n][1] + acc[n][2] + acc[n][3];
      qreg[n] += acc[n][0] * acc[n][0] + acc[n][1] * acc[n][1] +
                 acc[n][2] * acc[n][2] + acc[n][3] * acc[n][3];
    }
  }

#pragma unroll
  for (int n = 0; n < 8; n++) {
    float s0 = sreg[n], q0 = qreg[n];
    s0 += __shfl_xor(s0, 16); s0 += __shfl_xor(s0, 32);
    q0 += __shfl_xor(q0, 16); q0 += __shfl_xor(q0, 32);
    if (g == 0) {
      atomicAdd(&lsum[n * 16 + c15], s0);
      atomicAdd(&lsq[n * 16 + c15], q0);
    }
  }
  __syncthreads();
  if (t < 128) {
    float* dst = gstatR + (blockIdx.x & 31) * 256;  // 32-way replicated stats
    atomicAdd(&dst[t], lsum[t]);
    atomicAdd(&dst[128 + t], lsq[t]);
  }
}

// ---------------- pass 2: BN+LeakyReLU+4 head GEMMs+gated combine ----------------
// grid 256, 8 waves (2M x 4C), 16 tiles of 32 rows. B-fragments hoisted to
// registers (kills per-tile lwh ds_reads + bank conflicts); fast tanh/sigmoid.
#define HEAD_NT 16
__global__ __launch_bounds__(512, 2) void k_head(
    const u16* __restrict__ z, const float* __restrict__ tvec,
    const u16* __restrict__ whT, const float* __restrict__ biasc,
    const float* __restrict__ gstatR, const float* __restrict__ gamma,
    const float* __restrict__ beta, float* __restrict__ out) {
  __shared__ u16 lwh[512 * 128];     // 128KB, staged once, read once (hoist)
  __shared__ u16 lzn[2][32 * 128];   // 2 x 8KB, swizzled
  __shared__ float ls[128], lb[128];
  const int t = threadIdx.x;
  const int w = t >> 6, lane = t & 63;
  const int c15 = lane & 15, g = lane >> 4;
  const int mw = w >> 2, cw = w & 3;

  const long tile0 = (long)blockIdx.x * HEAD_NT;
  const int zrow = t >> 4, zci = (t & 15) * 8;

  // prefetch first z chunk before the heavy WheadT stage
  u16x8 zreg = *(const u16x8*)(z + (tile0 * 32 + zrow) * 128 + zci);

  for (int q = t; q < 8192; q += 512) {   // stage WheadT (coalesced)
    const int col = q >> 4;
    const int dst = (q * 16) ^ ((col & 7) << 4);
    *(u16x8*)((char*)lwh + dst) = *(const u16x8*)((const char*)whT + (size_t)q * 16);
  }
  // BN finalize folded in: reduce 32 stat replicas
  if (t < 128) {
    float s = 0.f, q = 0.f;
#pragma unroll
    for (int r = 0; r < 32; r++) {
      s += gstatR[r * 256 + t];
      q += gstatR[r * 256 + 128 + t];
    }
    const float inv = 1.f / (float)NROWS;
    const float mean = s * inv;
    const float var = q * inv - mean * mean;
    const float sc = gamma[t] * rsqrtf(var + 1e-5f);
    ls[t] = sc;
    lb[t] = beta[t] - mean * sc;
  }

  float biasr[8];
#pragma unroll
  for (int fi = 0; fi < 8; fi++) {
    const int hh = fi >> 1, p = fi & 1;
    biasr[fi] = biasc[hh * 128 + cw * 32 + p * 16 + c15];
  }
  __syncthreads();  // lwh + ls/lb ready

  // hoist ALL B-fragments to registers: 32 x bf16x8 (128 VGPR) — static indices
  bf16x8 breg[32];
#pragma unroll
  for (int ks = 0; ks < 4; ks++) {
#pragma unroll
    for (int fi = 0; fi < 8; fi++) {
      const int hh = fi >> 1, p = fi & 1;
      const int colg = hh * 128 + cw * 32 + p * 16 + c15;
      const int binner = ((ks * 32 + g * 8) * 2) ^ ((colg & 7) << 4);
      breg[ks * 8 + fi] = *(const bf16x8*)((const char*)lwh + colg * 256 + binner);
    }
  }

  for (int it = 0; it < HEAD_NT; it++) {
    const long r0 = (tile0 + it) * 32;
    const int pb = it & 1;
    {  // BN + LeakyReLU -> bf16 -> swizzled LDS (dbuf)
      union { u16x8 v; unsigned u[4]; } Z;
#pragma unroll
      for (int e = 0; e < 8; e += 2) {
        const int k = zci + e;
        float f0 = bf2f(zreg[e]) * ls[k] + lb[k];
        float f1 = bf2f(zreg[e + 1]) * ls[k + 1] + lb[k + 1];
        f0 = f0 > 0.f ? f0 : 0.01f * f0;
        f1 = f1 > 0.f ? f1 : 0.01f * f1;
        Z.u[e >> 1] = cvtpk(f0, f1);
      }
      const int dst = (zrow * 256 + zci * 2) ^ ((zrow & 7) << 4);
      *(u16x8*)((char*)lzn[pb] + dst) = Z.v;
    }
    if (it < HEAD_NT - 1)  // prefetch next tile's z (issues before barrier)
      zreg = *(const u16x8*)(z + ((tile0 + it + 1) * 32 + zrow) * 128 + zci);
    const float4 tq = *(const float4*)(tvec + r0 + mw * 16 + g * 4);
    __syncthreads();  // zn[pb] written by all waves

    f32x4 acc[8];
#pragma unroll
    for (int fi = 0; fi < 8; fi++) acc[fi] = (f32x4){0.f, 0.f, 0.f, 0.f};
#pragma unroll
    for (int ks = 0; ks < 4; ks++) {
      const int rowl = mw * 16 + c15;
      const int ainner = ((ks * 32 + g * 8) * 2) ^ ((rowl & 7) << 4);
      const bf16x8 af = *(const bf16x8*)((const char*)lzn[pb] + rowl * 256 + ainner);
#pragma unroll
      for (int fi = 0; fi < 8; fi++)
        acc[fi] = __builtin_amdgcn_mfma_f32_16x16x32_bf16(af, breg[ks * 8 + fi], acc[fi], 0, 0, 0);
    }

#pragma unroll
    for (int j = 0; j < 4; j++) {
      const long row = r0 + mw * 16 + g * 4 + j;
      const float tv = tq[j];
#pragma unroll
      for (int p = 0; p < 2; p++) {
        const float ug = acc[0 + p][j] + biasr[0 + p];
        const float uf = acc[2 + p][j] + biasr[2 + p];
        const float uh = acc[4 + p][j] + biasr[4 + p];
        const float ut = acc[6 + p][j] + biasr[6 + p];
        const float gg = tanh_f(ug);
        const float hv = tanh_f(uh);
        const float sig = frcp(1.f + __expf(-(ut + uf) * tv));
        out[row * 128 + cw * 32 + p * 16 + c15] = hv + sig * (gg - hv);
      }
    }
  }
}

// ---------------- launch ----------------
extern "C" void kernel_launch(void* const* d_in, const int* in_sizes, int n_in,
                              void* d_out, int out_size, void* d_ws, size_t ws_size,
                              hipStream_t stream) {
  const float* x     = (const float*)d_in[0];
  const float* h     = (const float*)d_in[1];
  const float* tv    = (const float*)d_in[2];
  const float* W0    = (const float*)d_in[3];
  const float* W1    = (const float*)d_in[4];
  const float* gamma = (const float*)d_in[5];
  const float* beta  = (const float*)d_in[6];
  const float* Wg    = (const float*)d_in[7];
  const float* bg    = (const float*)d_in[8];
  const float* Wf    = (const float*)d_in[9];
  const float* bf_   = (const float*)d_in[10];
  const float* Wh    = (const float*)d_in[11];
  const float* bh    = (const float*)d_in[12];
  const float* Wt    = (const float*)d_in[13];
  const float* bt    = (const float*)d_in[14];

  char* ws = (char*)d_ws;
  const size_t OFF_Z    = 0;                       // 33554432
  const size_t OFF_WC   = 33554432;                // 65536
  const size_t OFF_WH   = OFF_WC + 65536;          // 131072
  const size_t OFF_BIAS = OFF_WH + 131072;         // 2048
  const size_t OFF_STAT = OFF_BIAS + 2048;         // 32*256*4
  u16*   zbuf  = (u16*)(ws + OFF_Z);
  u16*   wcT   = (u16*)(ws + OFF_WC);
  u16*   whT   = (u16*)(ws + OFF_WH);
  float* biasc = (float*)(ws + OFF_BIAS);
  float* gstat = (float*)(ws + OFF_STAT);

  hipLaunchKernelGGL(k_prep_wc, dim3(32),  dim3(256), 0, stream, W0, W1, wcT);
  hipLaunchKernelGGL(k_prep_wh, dim3(256), dim3(256), 0, stream,
                     Wg, Wf, Wh, Wt, whT, bg, bf_, bh, bt, biasc, gstat);
  hipLaunchKernelGGL(k_gemm1,   dim3(512), dim3(512), 0, stream, x, h, wcT, zbuf, gstat);
  hipLaunchKernelGGL(k_head,    dim3(256), dim3(512), 0, stream,
                     zbuf, tv, whT, biasc, gstat, gamma, beta, (float*)d_out);
}

// Round 8
// 86.978 us; speedup vs baseline: 1.5314x; 1.0121x over previous
//
#include <hip/hip_runtime.h>

typedef unsigned short u16;
typedef __attribute__((ext_vector_type(8))) short bf16x8;
typedef __attribute__((ext_vector_type(8))) unsigned short u16x8;
typedef __attribute__((ext_vector_type(4))) float f32x4;

#define NROWS 131072

static __device__ __forceinline__ u16 f2bf(float f) {
  unsigned u = __float_as_uint(f);
  u += 0x7fffu + ((u >> 16) & 1u);   // RNE (prep-path only)
  return (u16)(u >> 16);
}
static __device__ __forceinline__ float bf2f(u16 v) {
  return __uint_as_float(((unsigned)v) << 16);
}
// HW packed RNE convert: low16 = bf16(lo), high16 = bf16(hi)
static __device__ __forceinline__ unsigned cvtpk(float lo, float hi) {
  unsigned r;
  asm("v_cvt_pk_bf16_f32 %0, %1, %2" : "=v"(r) : "v"(lo), "v"(hi));
  return r;
}
// fast reciprocal (v_rcp_f32, ~1e-7 rel err — fine vs 2% threshold)
static __device__ __forceinline__ float frcp(float x) {
  float r;
  asm("v_rcp_f32 %0, %1" : "=v"(r) : "v"(x));
  return r;
}
static __device__ __forceinline__ float tanh_f(float x) {
  x = fminf(fmaxf(x, -15.f), 15.f);
  const float t = __expf(2.f * x);
  return (t - 1.f) * frcp(t + 1.f);
}

// ---------------- prep kernels ----------------

__global__ void k_prep_wc(const float* __restrict__ W0,
                          const float* __restrict__ W1,
                          u16* __restrict__ wcT) {
  __shared__ float lw1[128 * 128];
  const int t = threadIdx.x;
  for (int i = t; i < 128 * 128; i += 256) lw1[i] = W1[i];
  __syncthreads();
  const int c = t & 127;
  for (int kk = (t >> 7); kk < 8; kk += 2) {
    const int k = blockIdx.x * 8 + kk;
    const float* w0r = W0 + k * 128;
    float a = 0.f;
#pragma unroll 8
    for (int j = 0; j < 128; j++) a = fmaf(w0r[j], lw1[j * 128 + c], a);
    wcT[c * 256 + k] = f2bf(a);
  }
}

__global__ void k_prep_wh(const float* __restrict__ Wg, const float* __restrict__ Wf,
                          const float* __restrict__ Wh, const float* __restrict__ Wt,
                          u16* __restrict__ whT,
                          const float* __restrict__ bg, const float* __restrict__ bf_,
                          const float* __restrict__ bh, const float* __restrict__ bt,
                          float* __restrict__ biasc, float* __restrict__ gstatR) {
  const int idx = blockIdx.x * 256 + threadIdx.x;  // 65536 total
  const int col = idx >> 7, k = idx & 127;
  const int hh = col >> 7, c = col & 127;
  const float* W = hh == 0 ? Wg : hh == 1 ? Wf : hh == 2 ? Wh : Wt;
  whT[col * 128 + k] = f2bf(W[k * 128 + c]);
  if (blockIdx.x < 32) gstatR[blockIdx.x * 256 + threadIdx.x] = 0.f;  // 32 replicas
  if (blockIdx.x == 32) {
    for (int i = threadIdx.x; i < 512; i += 256) {
      const int h2 = i >> 7, c2 = i & 127;
      const float* s = h2 == 0 ? bg : h2 == 1 ? bf_ : h2 == 2 ? bh : bt;
      biasc[i] = s[c2];
    }
  }
}

// ---------------- pass 1: z = cat(x,h) @ Wc (bf16 z + column stats) ----------------
// Round-4 structure (known-pass), minimal delta: flat a[16] full-tile preload
// (no ring, chunk i loaded at i, consumed at ks=i), launch_bounds (512,2),
// 4 row-tiles/block (grid 256).
__global__ __launch_bounds__(512, 2) void k_gemm1(
    const float* __restrict__ x, const float* __restrict__ h,
    const u16* __restrict__ wcT, u16* __restrict__ z,
    float* __restrict__ gstatR) {
  __shared__ u16 lwc[128 * 256];        // 64KB, XOR-swizzled
  __shared__ float lsum[128], lsq[128];
  const int t = threadIdx.x;
  const int w = t >> 6, lane = t & 63;
  const int c15 = lane & 15, g = lane >> 4;

  if (t < 128) lsum[t] = 0.f;
  else if (t < 256) lsq[t - 128] = 0.f;

  for (int q = t; q < 4096; q += 512) {   // stage WcT (16B chunks)
    const int c = q >> 5;
    const int dst = (q * 16) ^ ((c & 7) << 4);
    *(u16x8*)((char*)lwc + dst) = *(const u16x8*)((const char*)wcT + (size_t)q * 16);
  }
  __syncthreads();

  float sreg[8], qreg[8];
#pragma unroll
  for (int n = 0; n < 8; n++) { sreg[n] = 0.f; qreg[n] = 0.f; }

#pragma unroll 1
  for (int tile = 0; tile < 4; tile++) {
    const long row = (long)blockIdx.x * 512 + tile * 128 + w * 16 + c15;
    const float* xr = x + row * 128;
    const float* hr = h + row * 128;

    // flat preload: lane's FULL k-slice for this tile = 16 float4 (64 VGPR)
    float4 a[16];
#pragma unroll
    for (int i = 0; i < 8; i++) {
      const float* p = (i < 4 ? xr + i * 32 : hr + (i - 4) * 32) + g * 8;
      a[2 * i] = *(const float4*)p;
      a[2 * i + 1] = *(const float4*)(p + 4);
    }

    f32x4 acc[8];
#pragma unroll
    for (int n = 0; n < 8; n++) acc[n] = (f32x4){0.f, 0.f, 0.f, 0.f};

#pragma unroll
    for (int ks = 0; ks < 8; ks++) {
      union { bf16x8 v; unsigned u[4]; } U;
      U.u[0] = cvtpk(a[2 * ks].x, a[2 * ks].y);
      U.u[1] = cvtpk(a[2 * ks].z, a[2 * ks].w);
      U.u[2] = cvtpk(a[2 * ks + 1].x, a[2 * ks + 1].y);
      U.u[3] = cvtpk(a[2 * ks + 1].z, a[2 * ks + 1].w);
#pragma unroll
      for (int n = 0; n < 8; n++) {
        const int col = n * 16 + c15;
        const int inner = ((ks * 32 + g * 8) * 2) ^ ((col & 7) << 4);
        const bf16x8 bfr = *(const bf16x8*)((const char*)lwc + col * 512 + inner);
        acc[n] = __builtin_amdgcn_mfma_f32_16x16x32_bf16(U.v, bfr, acc[n], 0, 0, 0);
      }
    }

    // z write (bf16): C layout row=(lane>>4)*4+j, col=n*16+(lane&15)
    const long zrow = (long)blockIdx.x * 512 + tile * 128 + w * 16 + g * 4;
#pragma unroll
    for (int n = 0; n < 8; n++) {
      const int col = n * 16 + c15;
#pragma unroll
      for (int jp = 0; jp < 4; jp += 2) {
        const unsigned pk = cvtpk(acc[n][jp], acc[n][jp + 1]);
        z[(zrow + jp) * 128 + col] = (u16)pk;
        z[(zrow + jp + 1) * 128 + col] = (u16)(pk >> 16);
      }
      sreg[n] += acc[n][0] + acc[n][1] + acc[n][2] + acc[n][3];
      qreg[n] += acc[n][0] * acc[n][0] + acc[n][1] * acc[n][1] +
                 acc[n][2] * acc[n][2] + acc[n][3] * acc[n][3];
    }
  }

#pragma unroll
  for (int n = 0; n < 8; n++) {
    float s0 = sreg[n], q0 = qreg[n];
    s0 += __shfl_xor(s0, 16); s0 += __shfl_xor(s0, 32);
    q0 += __shfl_xor(q0, 16); q0 += __shfl_xor(q0, 32);
    if (g == 0) {
      atomicAdd(&lsum[n * 16 + c15], s0);
      atomicAdd(&lsq[n * 16 + c15], q0);
    }
  }
  __syncthreads();
  if (t < 128) {
    float* dst = gstatR + (blockIdx.x & 31) * 256;  // 32-way replicated stats
    atomicAdd(&dst[t], lsum[t]);
    atomicAdd(&dst[128 + t], lsq[t]);
  }
}

// ---------------- pass 2: BN+LeakyReLU+4 head GEMMs+gated combine ----------------
// ROUND-6 VERBATIM (pass, ~27us). grid 256, 8 waves, B-frags hoisted, fast math.
#define HEAD_NT 16
__global__ __launch_bounds__(512, 2) void k_head(
    const u16* __restrict__ z, const float* __restrict__ tvec,
    const u16* __restrict__ whT, const float* __restrict__ biasc,
    const float* __restrict__ gstatR, const float* __restrict__ gamma,
    const float* __restrict__ beta, float* __restrict__ out) {
  __shared__ u16 lwh[512 * 128];     // 128KB, staged once, read once (hoist)
  __shared__ u16 lzn[2][32 * 128];   // 2 x 8KB, swizzled
  __shared__ float ls[128], lb[128];
  const int t = threadIdx.x;
  const int w = t >> 6, lane = t & 63;
  const int c15 = lane & 15, g = lane >> 4;
  const int mw = w >> 2, cw = w & 3;

  const long tile0 = (long)blockIdx.x * HEAD_NT;
  const int zrow = t >> 4, zci = (t & 15) * 8;

  // prefetch first z chunk before the heavy WheadT stage
  u16x8 zreg = *(const u16x8*)(z + (tile0 * 32 + zrow) * 128 + zci);

  for (int q = t; q < 8192; q += 512) {   // stage WheadT (coalesced)
    const int col = q >> 4;
    const int dst = (q * 16) ^ ((col & 7) << 4);
    *(u16x8*)((char*)lwh + dst) = *(const u16x8*)((const char*)whT + (size_t)q * 16);
  }
  // BN finalize folded in: reduce 32 stat replicas
  if (t < 128) {
    float s = 0.f, q = 0.f;
#pragma unroll
    for (int r = 0; r < 32; r++) {
      s += gstatR[r * 256 + t];
      q += gstatR[r * 256 + 128 + t];
    }
    const float inv = 1.f / (float)NROWS;
    const float mean = s * inv;
    const float var = q * inv - mean * mean;
    const float sc = gamma[t] * rsqrtf(var + 1e-5f);
    ls[t] = sc;
    lb[t] = beta[t] - mean * sc;
  }

  float biasr[8];
#pragma unroll
  for (int fi = 0; fi < 8; fi++) {
    const int hh = fi >> 1, p = fi & 1;
    biasr[fi] = biasc[hh * 128 + cw * 32 + p * 16 + c15];
  }
  __syncthreads();  // lwh + ls/lb ready

  // hoist ALL B-fragments to registers: 32 x bf16x8 (128 VGPR) — static indices
  bf16x8 breg[32];
#pragma unroll
  for (int ks = 0; ks < 4; ks++) {
#pragma unroll
    for (int fi = 0; fi < 8; fi++) {
      const int hh = fi >> 1, p = fi & 1;
      const int colg = hh * 128 + cw * 32 + p * 16 + c15;
      const int binner = ((ks * 32 + g * 8) * 2) ^ ((colg & 7) << 4);
      breg[ks * 8 + fi] = *(const bf16x8*)((const char*)lwh + colg * 256 + binner);
    }
  }

  for (int it = 0; it < HEAD_NT; it++) {
    const long r0 = (tile0 + it) * 32;
    const int pb = it & 1;
    {  // BN + LeakyReLU -> bf16 -> swizzled LDS (dbuf)
      union { u16x8 v; unsigned u[4]; } Z;
#pragma unroll
      for (int e = 0; e < 8; e += 2) {
        const int k = zci + e;
        float f0 = bf2f(zreg[e]) * ls[k] + lb[k];
        float f1 = bf2f(zreg[e + 1]) * ls[k + 1] + lb[k + 1];
        f0 = f0 > 0.f ? f0 : 0.01f * f0;
        f1 = f1 > 0.f ? f1 : 0.01f * f1;
        Z.u[e >> 1] = cvtpk(f0, f1);
      }
      const int dst = (zrow * 256 + zci * 2) ^ ((zrow & 7) << 4);
      *(u16x8*)((char*)lzn[pb] + dst) = Z.v;
    }
    if (it < HEAD_NT - 1)  // prefetch next tile's z (issues before barrier)
      zreg = *(const u16x8*)(z + ((tile0 + it + 1) * 32 + zrow) * 128 + zci);
    const float4 tq = *(const float4*)(tvec + r0 + mw * 16 + g * 4);
    __syncthreads();  // zn[pb] written by all waves

    f32x4 acc[8];
#pragma unroll
    for (int fi = 0; fi < 8; fi++) acc[fi] = (f32x4){0.f, 0.f, 0.f, 0.f};
#pragma unroll
    for (int ks = 0; ks < 4; ks++) {
      const int rowl = mw * 16 + c15;
      const int ainner = ((ks * 32 + g * 8) * 2) ^ ((rowl & 7) << 4);
      const bf16x8 af = *(const bf16x8*)((const char*)lzn[pb] + rowl * 256 + ainner);
#pragma unroll
      for (int fi = 0; fi < 8; fi++)
        acc[fi] = __builtin_amdgcn_mfma_f32_16x16x32_bf16(af, breg[ks * 8 + fi], acc[fi], 0, 0, 0);
    }

#pragma unroll
    for (int j = 0; j < 4; j++) {
      const long row = r0 + mw * 16 + g * 4 + j;
      const float tv = tq[j];
#pragma unroll
      for (int p = 0; p < 2; p++) {
        const float ug = acc[0 + p][j] + biasr[0 + p];
        const float uf = acc[2 + p][j] + biasr[2 + p];
        const float uh = acc[4 + p][j] + biasr[4 + p];
        const float ut = acc[6 + p][j] + biasr[6 + p];
        const float gg = tanh_f(ug);
        const float hv = tanh_f(uh);
        const float sig = frcp(1.f + __expf(-(ut + uf) * tv));
        out[row * 128 + cw * 32 + p * 16 + c15] = hv + sig * (gg - hv);
      }
    }
  }
}

// ---------------- launch ----------------
extern "C" void kernel_launch(void* const* d_in, const int* in_sizes, int n_in,
                              void* d_out, int out_size, void* d_ws, size_t ws_size,
                              hipStream_t stream) {
  const float* x     = (const float*)d_in[0];
  const float* h     = (const float*)d_in[1];
  const float* tv    = (const float*)d_in[2];
  const float* W0    = (const float*)d_in[3];
  const float* W1    = (const float*)d_in[4];
  const float* gamma = (const float*)d_in[5];
  const float* beta  = (const float*)d_in[6];
  const float* Wg    = (const float*)d_in[7];
  const float* bg    = (const float*)d_in[8];
  const float* Wf    = (const float*)d_in[9];
  const float* bf_   = (const float*)d_in[10];
  const float* Wh    = (const float*)d_in[11];
  const float* bh    = (const float*)d_in[12];
  const float* Wt    = (const float*)d_in[13];
  const float* bt    = (const float*)d_in[14];

  char* ws = (char*)d_ws;
  const size_t OFF_Z    = 0;                       // 33554432
  const size_t OFF_WC   = 33554432;                // 65536
  const size_t OFF_WH   = OFF_WC + 65536;          // 131072
  const size_t OFF_BIAS = OFF_WH + 131072;         // 2048
  const size_t OFF_STAT = OFF_BIAS + 2048;         // 32*256*4
  u16*   zbuf  = (u16*)(ws + OFF_Z);
  u16*   wcT   = (u16*)(ws + OFF_WC);
  u16*   whT   = (u16*)(ws + OFF_WH);
  float* biasc = (float*)(ws + OFF_BIAS);
  float* gstat = (float*)(ws + OFF_STAT);

  hipLaunchKernelGGL(k_prep_wc, dim3(32),  dim3(256), 0, stream, W0, W1, wcT);
  hipLaunchKernelGGL(k_prep_wh, dim3(256), dim3(256), 0, stream,
                     Wg, Wf, Wh, Wt, whT, bg, bf_, bh, bt, biasc, gstat);
  hipLaunchKernelGGL(k_gemm1,   dim3(256), dim3(512), 0, stream, x, h, wcT, zbuf, gstat);
  hipLaunchKernelGGL(k_head,    dim3(256), dim3(512), 0, stream,
                     zbuf, tv, whT, biasc, gstat, gamma, beta, (float*)d_out);
}

// Round 10
// 86.118 us; speedup vs baseline: 1.5467x; 1.0100x over previous
//
#include <hip/hip_runtime.h>

typedef unsigned short u16;
typedef __attribute__((ext_vector_type(8))) short bf16x8;
typedef __attribute__((ext_vector_type(8))) unsigned short u16x8;
typedef __attribute__((ext_vector_type(4))) float f32x4;

#define NROWS 131072

static __device__ __forceinline__ u16 f2bf(float f) {
  unsigned u = __float_as_uint(f);
  u += 0x7fffu + ((u >> 16) & 1u);   // RNE (prep-path only)
  return (u16)(u >> 16);
}
static __device__ __forceinline__ float bf2f(u16 v) {
  return __uint_as_float(((unsigned)v) << 16);
}
// HW packed RNE convert: low16 = bf16(lo), high16 = bf16(hi)
static __device__ __forceinline__ unsigned cvtpk(float lo, float hi) {
  unsigned r;
  asm("v_cvt_pk_bf16_f32 %0, %1, %2" : "=v"(r) : "v"(lo), "v"(hi));
  return r;
}
// fast reciprocal (v_rcp_f32, ~1e-7 rel err — fine vs 2% threshold)
static __device__ __forceinline__ float frcp(float x) {
  float r;
  asm("v_rcp_f32 %0, %1" : "=v"(r) : "v"(x));
  return r;
}
static __device__ __forceinline__ float tanh_f(float x) {
  x = fminf(fmaxf(x, -15.f), 15.f);
  const float t = __expf(2.f * x);
  return (t - 1.f) * frcp(t + 1.f);
}

// ---------------- prep kernels ----------------

__global__ void k_prep_wc(const float* __restrict__ W0,
                          const float* __restrict__ W1,
                          u16* __restrict__ wcT) {
  __shared__ float lw1[128 * 128];
  const int t = threadIdx.x;
  for (int i = t; i < 128 * 128; i += 256) lw1[i] = W1[i];
  __syncthreads();
  const int c = t & 127;
  for (int kk = (t >> 7); kk < 8; kk += 2) {
    const int k = blockIdx.x * 8 + kk;
    const float* w0r = W0 + k * 128;
    float a = 0.f;
#pragma unroll 8
    for (int j = 0; j < 128; j++) a = fmaf(w0r[j], lw1[j * 128 + c], a);
    wcT[c * 256 + k] = f2bf(a);
  }
}

__global__ void k_prep_wh(const float* __restrict__ Wg, const float* __restrict__ Wf,
                          const float* __restrict__ Wh, const float* __restrict__ Wt,
                          u16* __restrict__ whT,
                          const float* __restrict__ bg, const float* __restrict__ bf_,
                          const float* __restrict__ bh, const float* __restrict__ bt,
                          float* __restrict__ biasc, float* __restrict__ gstatR) {
  const int idx = blockIdx.x * 256 + threadIdx.x;  // 65536 total
  const int col = idx >> 7, k = idx & 127;
  const int hh = col >> 7, c = col & 127;
  const float* W = hh == 0 ? Wg : hh == 1 ? Wf : hh == 2 ? Wh : Wt;
  whT[col * 128 + k] = f2bf(W[k * 128 + c]);
  if (blockIdx.x < 32) gstatR[blockIdx.x * 256 + threadIdx.x] = 0.f;  // 32 replicas
  if (blockIdx.x == 32) {
    for (int i = threadIdx.x; i < 512; i += 256) {
      const int h2 = i >> 7, c2 = i & 127;
      const float* s = h2 == 0 ? bg : h2 == 1 ? bf_ : h2 == 2 ? bh : bt;
      biasc[i] = s[c2];
    }
  }
}

// ---------------- pass 1: z = cat(x,h) @ Wc (bf16 z + column stats) ----------------
// ROUND-8 STRUCTURE VERBATIM (known-pass) + ONE change: volatile-asm use-pin of
// all 16 preloaded float4 (defeats load-sinking; VGPR=64 in r8 proved loads were
// serialized). Batch-issue 16 loads -> one vmcnt wait -> stall-free MFMA chain.
__global__ __launch_bounds__(512, 2) void k_gemm1(
    const float* __restrict__ x, const float* __restrict__ h,
    const u16* __restrict__ wcT, u16* __restrict__ z,
    float* __restrict__ gstatR) {
  __shared__ u16 lwc[128 * 256];        // 64KB, XOR-swizzled
  __shared__ float lsum[128], lsq[128];
  const int t = threadIdx.x;
  const int w = t >> 6, lane = t & 63;
  const int c15 = lane & 15, g = lane >> 4;

  if (t < 128) lsum[t] = 0.f;
  else if (t < 256) lsq[t - 128] = 0.f;

  for (int q = t; q < 4096; q += 512) {   // stage WcT (16B chunks)
    const int c = q >> 5;
    const int dst = (q * 16) ^ ((c & 7) << 4);
    *(u16x8*)((char*)lwc + dst) = *(const u16x8*)((const char*)wcT + (size_t)q * 16);
  }
  __syncthreads();

  float sreg[8], qreg[8];
#pragma unroll
  for (int n = 0; n < 8; n++) { sreg[n] = 0.f; qreg[n] = 0.f; }

#pragma unroll 1
  for (int tile = 0; tile < 4; tile++) {
    const long row = (long)blockIdx.x * 512 + tile * 128 + w * 16 + c15;
    const float* xr = x + row * 128;
    const float* hr = h + row * 128;

    // flat preload: lane's FULL k-slice for this tile = 16 float4 (64 VGPR)
    f32x4 a[16];
#pragma unroll
    for (int i = 0; i < 8; i++) {
      const float* p = (i < 4 ? xr + i * 32 : hr + (i - 4) * 32) + g * 8;
      a[2 * i] = *(const f32x4*)p;
      a[2 * i + 1] = *(const f32x4*)(p + 4);
    }
    // pin: volatile asm USE of all 16 values — loads must all be issued and
    // resolved here (one batched vmcnt wait), cannot be sunk into the k-loop.
    asm volatile("" :: "v"(a[0]), "v"(a[1]), "v"(a[2]), "v"(a[3]),
                       "v"(a[4]), "v"(a[5]), "v"(a[6]), "v"(a[7]),
                       "v"(a[8]), "v"(a[9]), "v"(a[10]), "v"(a[11]),
                       "v"(a[12]), "v"(a[13]), "v"(a[14]), "v"(a[15]));

    f32x4 acc[8];
#pragma unroll
    for (int n = 0; n < 8; n++) acc[n] = (f32x4){0.f, 0.f, 0.f, 0.f};

#pragma unroll
    for (int ks = 0; ks < 8; ks++) {
      union { bf16x8 v; unsigned u[4]; } U;
      U.u[0] = cvtpk(a[2 * ks][0], a[2 * ks][1]);
      U.u[1] = cvtpk(a[2 * ks][2], a[2 * ks][3]);
      U.u[2] = cvtpk(a[2 * ks + 1][0], a[2 * ks + 1][1]);
      U.u[3] = cvtpk(a[2 * ks + 1][2], a[2 * ks + 1][3]);
#pragma unroll
      for (int n = 0; n < 8; n++) {
        const int col = n * 16 + c15;
        const int inner = ((ks * 32 + g * 8) * 2) ^ ((col & 7) << 4);
        const bf16x8 bfr = *(const bf16x8*)((const char*)lwc + col * 512 + inner);
        acc[n] = __builtin_amdgcn_mfma_f32_16x16x32_bf16(U.v, bfr, acc[n], 0, 0, 0);
      }
    }

    // z write (bf16): C layout row=(lane>>4)*4+j, col=n*16+(lane&15)
    const long zrow = (long)blockIdx.x * 512 + tile * 128 + w * 16 + g * 4;
#pragma unroll
    for (int n = 0; n < 8; n++) {
      const int col = n * 16 + c15;
#pragma unroll
      for (int jp = 0; jp < 4; jp += 2) {
        const unsigned pk = cvtpk(acc[n][jp], acc[n][jp + 1]);
        z[(zrow + jp) * 128 + col] = (u16)pk;
        z[(zrow + jp + 1) * 128 + col] = (u16)(pk >> 16);
      }
      sreg[n] += acc[n][0] + acc[n][1] + acc[n][2] + acc[n][3];
      qreg[n] += acc[n][0] * acc[n][0] + acc[n][1] * acc[n][1] +
                 acc[n][2] * acc[n][2] + acc[n][3] * acc[n][3];
    }
  }

#pragma unroll
  for (int n = 0; n < 8; n++) {
    float s0 = sreg[n], q0 = qreg[n];
    s0 += __shfl_xor(s0, 16); s0 += __shfl_xor(s0, 32);
    q0 += __shfl_xor(q0, 16); q0 += __shfl_xor(q0, 32);
    if (g == 0) {
      atomicAdd(&lsum[n * 16 + c15], s0);
      atomicAdd(&lsq[n * 16 + c15], q0);
    }
  }
  __syncthreads();
  if (t < 128) {
    float* dst = gstatR + (blockIdx.x & 31) * 256;  // 32-way replicated stats
    atomicAdd(&dst[t], lsum[t]);
    atomicAdd(&dst[128 + t], lsq[t]);
  }
}

// ---------------- pass 2: BN+LeakyReLU+4 head GEMMs+gated combine ----------------
// ROUND-8 VERBATIM (pass, ~27us). grid 256, 8 waves, B-frags hoisted, fast math.
#define HEAD_NT 16
__global__ __launch_bounds__(512, 2) void k_head(
    const u16* __restrict__ z, const float* __restrict__ tvec,
    const u16* __restrict__ whT, const float* __restrict__ biasc,
    const float* __restrict__ gstatR, const float* __restrict__ gamma,
    const float* __restrict__ beta, float* __restrict__ out) {
  __shared__ u16 lwh[512 * 128];     // 128KB, staged once, read once (hoist)
  __shared__ u16 lzn[2][32 * 128];   // 2 x 8KB, swizzled
  __shared__ float ls[128], lb[128];
  const int t = threadIdx.x;
  const int w = t >> 6, lane = t & 63;
  const int c15 = lane & 15, g = lane >> 4;
  const int mw = w >> 2, cw = w & 3;

  const long tile0 = (long)blockIdx.x * HEAD_NT;
  const int zrow = t >> 4, zci = (t & 15) * 8;

  // prefetch first z chunk before the heavy WheadT stage
  u16x8 zreg = *(const u16x8*)(z + (tile0 * 32 + zrow) * 128 + zci);

  for (int q = t; q < 8192; q += 512) {   // stage WheadT (coalesced)
    const int col = q >> 4;
    const int dst = (q * 16) ^ ((col & 7) << 4);
    *(u16x8*)((char*)lwh + dst) = *(const u16x8*)((const char*)whT + (size_t)q * 16);
  }
  // BN finalize folded in: reduce 32 stat replicas
  if (t < 128) {
    float s = 0.f, q = 0.f;
#pragma unroll
    for (int r = 0; r < 32; r++) {
      s += gstatR[r * 256 + t];
      q += gstatR[r * 256 + 128 + t];
    }
    const float inv = 1.f / (float)NROWS;
    const float mean = s * inv;
    const float var = q * inv - mean * mean;
    const float sc = gamma[t] * rsqrtf(var + 1e-5f);
    ls[t] = sc;
    lb[t] = beta[t] - mean * sc;
  }

  float biasr[8];
#pragma unroll
  for (int fi = 0; fi < 8; fi++) {
    const int hh = fi >> 1, p = fi & 1;
    biasr[fi] = biasc[hh * 128 + cw * 32 + p * 16 + c15];
  }
  __syncthreads();  // lwh + ls/lb ready

  // hoist ALL B-fragments to registers: 32 x bf16x8 (128 VGPR) — static indices
  bf16x8 breg[32];
#pragma unroll
  for (int ks = 0; ks < 4; ks++) {
#pragma unroll
    for (int fi = 0; fi < 8; fi++) {
      const int hh = fi >> 1, p = fi & 1;
      const int colg = hh * 128 + cw * 32 + p * 16 + c15;
      const int binner = ((ks * 32 + g * 8) * 2) ^ ((colg & 7) << 4);
      breg[ks * 8 + fi] = *(const bf16x8*)((const char*)lwh + colg * 256 + binner);
    }
  }

  for (int it = 0; it < HEAD_NT; it++) {
    const long r0 = (tile0 + it) * 32;
    const int pb = it & 1;
    {  // BN + LeakyReLU -> bf16 -> swizzled LDS (dbuf)
      union { u16x8 v; unsigned u[4]; } Z;
#pragma unroll
      for (int e = 0; e < 8; e += 2) {
        const int k = zci + e;
        float f0 = bf2f(zreg[e]) * ls[k] + lb[k];
        float f1 = bf2f(zreg[e + 1]) * ls[k + 1] + lb[k + 1];
        f0 = f0 > 0.f ? f0 : 0.01f * f0;
        f1 = f1 > 0.f ? f1 : 0.01f * f1;
        Z.u[e >> 1] = cvtpk(f0, f1);
      }
      const int dst = (zrow * 256 + zci * 2) ^ ((zrow & 7) << 4);
      *(u16x8*)((char*)lzn[pb] + dst) = Z.v;
    }
    if (it < HEAD_NT - 1)  // prefetch next tile's z (issues before barrier)
      zreg = *(const u16x8*)(z + ((tile0 + it + 1) * 32 + zrow) * 128 + zci);
    const float4 tq = *(const float4*)(tvec + r0 + mw * 16 + g * 4);
    __syncthreads();  // zn[pb] written by all waves

    f32x4 acc[8];
#pragma unroll
    for (int fi = 0; fi < 8; fi++) acc[fi] = (f32x4){0.f, 0.f, 0.f, 0.f};
#pragma unroll
    for (int ks = 0; ks < 4; ks++) {
      const int rowl = mw * 16 + c15;
      const int ainner = ((ks * 32 + g * 8) * 2) ^ ((rowl & 7) << 4);
      const bf16x8 af = *(const bf16x8*)((const char*)lzn[pb] + rowl * 256 + ainner);
#pragma unroll
      for (int fi = 0; fi < 8; fi++)
        acc[fi] = __builtin_amdgcn_mfma_f32_16x16x32_bf16(af, breg[ks * 8 + fi], acc[fi], 0, 0, 0);
    }

#pragma unroll
    for (int j = 0; j < 4; j++) {
      const long row = r0 + mw * 16 + g * 4 + j;
      const float tv = tq[j];
#pragma unroll
      for (int p = 0; p < 2; p++) {
        const float ug = acc[0 + p][j] + biasr[0 + p];
        const float uf = acc[2 + p][j] + biasr[2 + p];
        const float uh = acc[4 + p][j] + biasr[4 + p];
        const float ut = acc[6 + p][j] + biasr[6 + p];
        const float gg = tanh_f(ug);
        const float hv = tanh_f(uh);
        const float sig = frcp(1.f + __expf(-(ut + uf) * tv));
        out[row * 128 + cw * 32 + p * 16 + c15] = hv + sig * (gg - hv);
      }
    }
  }
}

// ---------------- launch ----------------
extern "C" void kernel_launch(void* const* d_in, const int* in_sizes, int n_in,
                              void* d_out, int out_size, void* d_ws, size_t ws_size,
                              hipStream_t stream) {
  const float* x     = (const float*)d_in[0];
  const float* h     = (const float*)d_in[1];
  const float* tv    = (const float*)d_in[2];
  const float* W0    = (const float*)d_in[3];
  const float* W1    = (const float*)d_in[4];
  const float* gamma = (const float*)d_in[5];
  const float* beta  = (const float*)d_in[6];
  const float* Wg    = (const float*)d_in[7];
  const float* bg    = (const float*)d_in[8];
  const float* Wf    = (const float*)d_in[9];
  const float* bf_   = (const float*)d_in[10];
  const float* Wh    = (const float*)d_in[11];
  const float* bh    = (const float*)d_in[12];
  const float* Wt    = (const float*)d_in[13];
  const float* bt    = (const float*)d_in[14];

  char* ws = (char*)d_ws;
  const size_t OFF_Z    = 0;                       // 33554432
  const size_t OFF_WC   = 33554432;                // 65536
  const size_t OFF_WH   = OFF_WC + 65536;          // 131072
  const size_t OFF_BIAS = OFF_WH + 131072;         // 2048
  const size_t OFF_STAT = OFF_BIAS + 2048;         // 32*256*4
  u16*   zbuf  = (u16*)(ws + OFF_Z);
  u16*   wcT   = (u16*)(ws + OFF_WC);
  u16*   whT   = (u16*)(ws + OFF_WH);
  float* biasc = (float*)(ws + OFF_BIAS);
  float* gstat = (float*)(ws + OFF_STAT);

  hipLaunchKernelGGL(k_prep_wc, dim3(32),  dim3(256), 0, stream, W0, W1, wcT);
  hipLaunchKernelGGL(k_prep_wh, dim3(256), dim3(256), 0, stream,
                     Wg, Wf, Wh, Wt, whT, bg, bf_, bh, bt, biasc, gstat);
  hipLaunchKernelGGL(k_gemm1,   dim3(256), dim3(512), 0, stream, x, h, wcT, zbuf, gstat);
  hipLaunchKernelGGL(k_head,    dim3(256), dim3(512), 0, stream,
                     zbuf, tv, whT, biasc, gstat, gamma, beta, (float*)d_out);
}